// Round 8
// baseline (3065.773 us; speedup 1.0000x reference)
//
#include <hip/hip_runtime.h>
#include <hip/hip_fp16.h>
#include <stdint.h>

#define B_  32
#define S_  32
#define V_  100
#define HD_ 32
#define HID_ 64
#define ND_ 10
#define NROW (B_*V_)
#define NFRAG 58

// ---- workspace float offsets ----
#define WO_EP    14848      // NFRAG*64*4 floats of frags before this
#define WO_ACC   24848
#define WO_LTLOG 28048

typedef __attribute__((ext_vector_type(8))) _Float16 f16x8;
typedef __attribute__((ext_vector_type(4))) float f32x4;

#define LGKM_FENCE asm volatile("s_waitcnt lgkmcnt(0)" ::: "memory")

// ---------------- threefry2x32 (JAX-compatible, verified) ----------------
__host__ __device__ inline void tf2x32(uint32_t k0, uint32_t k1,
                                       uint32_t& x0, uint32_t& x1) {
  uint32_t ks0 = k0, ks1 = k1, ks2 = k0 ^ k1 ^ 0x1BD11BDAu;
#define TFR(r) { x0 += x1; x1 = (x1 << (r)) | (x1 >> (32 - (r))); x1 ^= x0; }
  x0 += ks0; x1 += ks1;
  TFR(13) TFR(15) TFR(26) TFR(6)
  x0 += ks1; x1 += ks2 + 1u;
  TFR(17) TFR(29) TFR(16) TFR(24)
  x0 += ks2; x1 += ks0 + 2u;
  TFR(13) TFR(15) TFR(26) TFR(6)
  x0 += ks0; x1 += ks1 + 3u;
  TFR(17) TFR(29) TFR(16) TFR(24)
  x0 += ks1; x1 += ks2 + 4u;
  TFR(13) TFR(15) TFR(26) TFR(6)
  x0 += ks2; x1 += ks0 + 5u;
#undef TFR
}

// ---------------- erfinv (XLA / Giles f32 polynomial) ----------------
__device__ __forceinline__ float erfinv_f(float x) {
  float w = -log1pf(-x * x);
  float p;
  if (w < 5.0f) {
    w -= 2.5f;
    p = 2.81022636e-08f;
    p = fmaf(p, w, 3.43273939e-07f);
    p = fmaf(p, w, -3.5233877e-06f);
    p = fmaf(p, w, -4.39150654e-06f);
    p = fmaf(p, w, 0.00021858087f);
    p = fmaf(p, w, -0.00125372503f);
    p = fmaf(p, w, -0.00417768164f);
    p = fmaf(p, w, 0.246640727f);
    p = fmaf(p, w, 1.50140941f);
  } else {
    w = sqrtf(w) - 3.0f;
    p = -0.000200214257f;
    p = fmaf(p, w, 0.000100950558f);
    p = fmaf(p, w, 0.00134934322f);
    p = fmaf(p, w, -0.00367342844f);
    p = fmaf(p, w, 0.00573950773f);
    p = fmaf(p, w, -0.0076224613f);
    p = fmaf(p, w, 0.00943887047f);
    p = fmaf(p, w, 1.00167406f);
    p = fmaf(p, w, 2.83297682f);
  }
  return p * x;
}

// ---------------- fast device math ----------------
__device__ __forceinline__ float tanh_e(float x) {
  float e = __builtin_amdgcn_exp2f(x * 2.885390082f);
  return 1.0f - 2.0f * __builtin_amdgcn_rcpf(e + 1.0f);
}
__device__ __forceinline__ float softplus_fast(float x) {
  return fmaxf(x, 0.0f) + __logf(1.0f + __expf(-fabsf(x)));
}
__device__ __forceinline__ unsigned short f16b(float x) {
  __half h = __float2half(x);
  return *reinterpret_cast<unsigned short*>(&h);
}
__device__ __forceinline__ uint32_t pk2(float a, float b) {
  return (uint32_t)f16b(a) | ((uint32_t)f16b(b) << 16);
}
__device__ __forceinline__ f32x4 MF(f16x8 a, f16x8 b, f32x4 c) {
  return __builtin_amdgcn_mfma_f32_16x16x32_f16(a, b, c, 0, 0, 0);
}

struct AllK { uint32_t k[310][2]; };

// noise values for one wave-lane: v = t*4+reg -> (row = row0+4g+reg, dim = li+16t)
__device__ __forceinline__ void noise8(int row0, int lane, uint32_t k0, uint32_t k1,
                                       float* n) {
  int g = lane >> 4, li = lane & 15;
#pragma unroll
  for (int v = 0; v < 8; ++v) {
    int reg = v & 3, t = v >> 2;
    int row = row0 + 4 * g + reg;
    uint32_t x0 = 0u, x1 = (uint32_t)(row * HD_ + li + 16 * t);
    tf2x32(k0, k1, x0, x1);
    uint32_t bits = x0 ^ x1;
    float fr = __uint_as_float(0x3f800000u | (bits >> 9)) - 1.0f;
    const float LOW = -0.99999994f;
    float u = fmaxf(LOW, fr * 2.0f + LOW);
    n[v] = 1.4142135f * erfinv_f(u);
  }
}

// ---------------- prep: 58 f16 MFMA B-fragments + edge_prob ----------------
// K-perm rule (round-6 bug fix):
//   hperm (A from hTl/pair, two separate 32-dim regions): k = k0 + ((sl>>1)+16*(sl&1))
//   act-perm (A from act 64-col permuted array):          k = perm_a(k0+sl)
__global__ void prep_k(const float* __restrict__ fW1, const float* __restrict__ gW1,
                       const float* __restrict__ fW2, const float* __restrict__ gW2,
                       const float* __restrict__ fW3, const float* __restrict__ gW3,
                       const float* __restrict__ eW1, const float* __restrict__ eW2,
                       const float* __restrict__ mW1, const float* __restrict__ mW2,
                       const float* __restrict__ jW1, const float* __restrict__ jW2,
                       const float* __restrict__ logits, float* __restrict__ ws) {
  int tid = blockIdx.x * 256 + threadIdx.x;
  if (tid < NFRAG * 64) {
    int fid = tid >> 6, lane = tid & 63;
    int g = lane >> 4, li = lane & 15;
    const float* src; int k0 = 0, n0 = 0, ncol = HID_; bool hperm = false, col0 = false;
    if (fid < 4)       { src = fW1; n0 = 16 * fid;       hperm = true; }
    else if (fid < 8)  { src = gW1; n0 = 16 * (fid - 4); hperm = true; }
    else if (fid < 16) { int q = fid - 8;  src = fW2; n0 = 16 * (q >> 1); k0 = 32 * (q & 1); }
    else if (fid < 24) { int q = fid - 16; src = gW2; n0 = 16 * (q >> 1); k0 = 32 * (q & 1); }
    else if (fid < 28) { int q = fid - 24; src = fW3; n0 = 16 * (q >> 1); k0 = 32 * (q & 1); ncol = HD_; }
    else if (fid < 32) { int q = fid - 28; src = gW3; n0 = 16 * (q >> 1); k0 = 32 * (q & 1); ncol = HD_; }
    else if (fid < 36) { src = eW1; n0 = 16 * (fid - 32); hperm = true; }
    else if (fid < 38) { src = eW2; k0 = 32 * (fid - 36); col0 = true; }
    else if (fid < 46) { int q = fid - 38; src = mW1; k0 = 32 * (q >> 2); n0 = 16 * (q & 3); hperm = true; }
    else if (fid < 50) { int q = fid - 46; src = mW2; k0 = 32 * (q >> 1); n0 = 16 * (q & 1); ncol = HD_; }
    else if (fid < 54) { src = jW1; n0 = 16 * (fid - 50); hperm = true; }
    else               { int q = fid - 54; src = jW2; k0 = 32 * (q >> 1); n0 = 16 * (q & 1); ncol = HD_; }
    unsigned short v[8];
#pragma unroll
    for (int j = 0; j < 8; ++j) {
      int sl = 8 * g + j;
      int k;
      if (hperm) k = k0 + ((sl >> 1) + 16 * (sl & 1));
      else { int s2 = k0 + sl; k = (s2 >> 2) + 16 * (s2 & 3); }
      float x;
      if (col0) x = (li == 0) ? src[k] : 0.0f;
      else      x = src[k * ncol + (n0 + li)];
      v[j] = f16b(x);
    }
    uint4 o;
    o.x = (uint32_t)v[0] | ((uint32_t)v[1] << 16);
    o.y = (uint32_t)v[2] | ((uint32_t)v[3] << 16);
    o.z = (uint32_t)v[4] | ((uint32_t)v[5] << 16);
    o.w = (uint32_t)v[6] | ((uint32_t)v[7] << 16);
    ((uint4*)ws)[fid * 64 + lane] = o;
  } else if (tid < NFRAG * 64 + V_ * V_) {
    int idx = tid - NFRAG * 64;
    float l0v = logits[idx], l1v = logits[V_ * V_ + idx];
    float mx = fmaxf(l0v, l1v);
    float e0 = expf(l0v - mx), e1 = expf(l1v - mx);
    ws[WO_EP + idx] = e1 / (e0 + e1);
  }
}

// ---------------- persistent chain kernel: 1 block per batch, 7 waves ----------------
__launch_bounds__(448, 2)
__global__ void chain_k(const float* __restrict__ time_, const int* __restrict__ type_,
                        const float* __restrict__ mask_, const float* __restrict__ wsf,
                        const float* __restrict__ fb1, const float* __restrict__ fb2,
                        const float* __restrict__ fb3, const float* __restrict__ gb1,
                        const float* __restrict__ gb2, const float* __restrict__ gb3,
                        const float* __restrict__ eb1, const float* __restrict__ eb2,
                        const float* __restrict__ fW1, const float* __restrict__ gW1,
                        const float* __restrict__ mb1, const float* __restrict__ mb2,
                        const float* __restrict__ jb1, const float* __restrict__ jb2,
                        const float* __restrict__ h0,
                        float* __restrict__ acc, float* __restrict__ ltlog,
                        float* __restrict__ dout, AllK ak) {
  __shared__ f16x8 wl[22 * 64];                 // L1f0-3,L1g4-7,e1 8-11,e2 12-13,w3f 14-17,w3g 18-21
  __shared__ unsigned short actF[7][16 * 72];
  __shared__ unsigned short actG[7][16 * 72];
  __shared__ unsigned short hTl[7][16 * 40];
  __shared__ float sendv[32];

  const int w = threadIdx.x >> 6;      // wave = tile 0..6
  const int lane = threadIdx.x & 63;
  const int g = lane >> 4, li = lane & 15;
  const int b = blockIdx.x;
  const int row0 = b * V_ + w * 16;
  const f16x8* WBv = (const f16x8*)wsf;
  const float* ep = wsf + WO_EP;

  // ---- prologue: weights ----
  for (int i = threadIdx.x; i < 22 * 64; i += 448) {
    int q = i >> 6, l2 = i & 63;
    int src = (q < 8) ? q : ((q < 14) ? q + 24 : q + 10);
    wl[i] = WBv[src * 64 + l2];
  }
  f16x8 w2f[8], w2g[8];
#pragma unroll
  for (int i = 0; i < 8; ++i) w2f[i] = WBv[(8 + i) * 64 + lane];
#pragma unroll
  for (int i = 0; i < 8; ++i) w2g[i] = WBv[(16 + i) * 64 + lane];

  float fb1v[4], gb1v[4], fb2v[4], gb2v[4], eb1v[4], fw32[4], fw33[4], gw32[4];
  float mb1v[4], jb1v[4];
#pragma unroll
  for (int nt = 0; nt < 4; ++nt) {
    int n = li + 16 * nt;
    fb1v[nt] = fb1[n]; gb1v[nt] = gb1[n];
    fb2v[nt] = fb2[n]; gb2v[nt] = gb2[n];
    eb1v[nt] = eb1[n];
    fw32[nt] = fW1[32 * HID_ + n]; fw33[nt] = fW1[33 * HID_ + n];
    gw32[nt] = gW1[32 * HID_ + n];
    mb1v[nt] = mb1[n]; jb1v[nt] = jb1[n];
  }
  float fb3v[2], gb3v[2], mb2v[2], jb2v[2];
#pragma unroll
  for (int nt = 0; nt < 2; ++nt) {
    fb3v[nt] = fb3[li + 16 * nt]; gb3v[nt] = gb3[li + 16 * nt];
    mb2v[nt] = mb2[li + 16 * nt]; jb2v[nt] = jb2[li + 16 * nt];
  }
  const float eb2v = eb2[0];

  // ---- h init: broadcast(h0) ----
  float hv[2][4];
#pragma unroll
  for (int t = 0; t < 2; ++t)
#pragma unroll
    for (int reg = 0; reg < 4; ++reg) {
      int v = w * 16 + 4 * g + reg; if (v > V_ - 1) v = V_ - 1;
      hv[t][reg] = h0[v * HD_ + li + 16 * t];
    }

  __syncthreads();

#pragma unroll
  for (int reg = 0; reg < 4; ++reg)
    *(uint32_t*)&hTl[w][(4 * g + reg) * 40 + 2 * li] = pk2(hv[0][reg], hv[1][reg]);
  LGKM_FENCE;

  auto echain = [&](float* lout) {
    f16x8 ahe = *(const f16x8*)&hTl[w][li * 40 + 8 * g];
    f32x4 ce[4];
#pragma unroll
    for (int nt = 0; nt < 4; ++nt) {
      f32x4 c = {eb1v[nt], eb1v[nt], eb1v[nt], eb1v[nt]};
      ce[nt] = MF(ahe, wl[(8 + nt) * 64 + lane], c);
    }
#pragma unroll
    for (int reg = 0; reg < 4; ++reg) {
      uint2 u;
      u.x = pk2(tanh_e(ce[0][reg]), tanh_e(ce[1][reg]));
      u.y = pk2(tanh_e(ce[2][reg]), tanh_e(ce[3][reg]));
      *(uint2*)&actF[w][(4 * g + reg) * 72 + 4 * li] = u;
    }
    LGKM_FENCE;
    f16x8 ae0 = *(const f16x8*)&actF[w][li * 72 + 8 * g];
    f16x8 ae1 = *(const f16x8*)&actF[w][li * 72 + 32 + 8 * g];
    f32x4 c2 = {eb2v, eb2v, eb2v, eb2v};
    c2 = MF(ae0, wl[12 * 64 + lane], c2);
    c2 = MF(ae1, wl[13 * 64 + lane], c2);
#pragma unroll
    for (int reg = 0; reg < 4; ++reg) lout[reg] = softplus_fast(c2[reg]);
  };

  // ---- l0 (pre-msg), outputs for s=0 ----
  float l0a[4];
  echain(l0a);
  float accv[4] = {0.f, 0.f, 0.f, 0.f};
  float lprev[4], prevl_r[4] = {0.f, 0.f, 0.f, 0.f};
  float prevt_r = 0.f;
  if (li == 0) {
    int ev0 = type_[b * S_];
    float m0 = mask_[b * S_];
#pragma unroll
    for (int reg = 0; reg < 4; ++reg) {
      int v = w * 16 + 4 * g + reg;
      if (v < V_) {
        dout[1 + (b * S_ + 0) * V_ + v] = l0a[reg];
        if (v == ev0) ltlog[b] = logf(l0a[reg] + 1e-16f) * m0;
      }
    }
  }

  // ================= interval chain =================
  for (int s = 1; s <= 31; ++s) {
    const int ev = type_[b * S_ + s - 1];
    __syncthreads();                      // prior interval's sendv reads done
    if (w == (ev >> 4)) {                 // tile holding row ev publishes PRE-msg send h
      int rr = ev & 15;
      if (g == (rr >> 2)) {
        int rg = rr & 3;
        float v0 = (rg == 0) ? hv[0][0] : (rg == 1) ? hv[0][1] : (rg == 2) ? hv[0][2] : hv[0][3];
        float v1 = (rg == 0) ? hv[1][0] : (rg == 1) ? hv[1][1] : (rg == 2) ? hv[1][2] : hv[1][3];
        sendv[li] = v0; sendv[li + 16] = v1;
      }
    }
    __syncthreads();

    // ---- msg phase (MFMA) ----
    {
      uint32_t su = pk2(sendv[li], sendv[li + 16]);
#pragma unroll
      for (int reg = 0; reg < 4; ++reg) {
        *(uint32_t*)&actF[w][(4 * g + reg) * 72 + 2 * li] = su;
        *(uint32_t*)&actG[w][(4 * g + reg) * 72 + 2 * li] = pk2(hv[0][reg], hv[1][reg]);
      }
      LGKM_FENCE;
      f16x8 ap0 = *(const f16x8*)&actF[w][li * 72 + 8 * g];
      f16x8 ap1 = *(const f16x8*)&actG[w][li * 72 + 8 * g];
      f32x4 cm[4];
#pragma unroll
      for (int nt = 0; nt < 4; ++nt) {
        f32x4 c = {mb1v[nt], mb1v[nt], mb1v[nt], mb1v[nt]};
        c = MF(ap0, WBv[(38 + nt) * 64 + lane], c);
        cm[nt] = MF(ap1, WBv[(42 + nt) * 64 + lane], c);
      }
#pragma unroll
      for (int reg = 0; reg < 4; ++reg) {
        uint2 u;
        u.x = pk2(tanh_e(cm[0][reg]), tanh_e(cm[1][reg]));
        u.y = pk2(tanh_e(cm[2][reg]), tanh_e(cm[3][reg]));
        *(uint2*)&actF[w][(4 * g + reg) * 72 + 4 * li] = u;
      }
      LGKM_FENCE;
      f16x8 am0 = *(const f16x8*)&actF[w][li * 72 + 8 * g];
      f16x8 am1 = *(const f16x8*)&actF[w][li * 72 + 32 + 8 * g];
      f32x4 mm[2];
#pragma unroll
      for (int nt = 0; nt < 2; ++nt) {
        f32x4 c = {mb2v[nt], mb2v[nt], mb2v[nt], mb2v[nt]};
        c = MF(am0, WBv[(46 + nt) * 64 + lane], c);
        mm[nt] = MF(am1, WBv[(48 + nt) * 64 + lane], c);
      }
#pragma unroll
      for (int reg = 0; reg < 4; ++reg) {
        int v = w * 16 + 4 * g + reg; int vc = (v < V_) ? v : (V_ - 1);
        float p = ep[ev * V_ + vc];
        hv[0][reg] += mm[0][reg] * p;
        hv[1][reg] += mm[1][reg] * p;
      }
      if (w == (ev >> 4)) {               // jump on post-msg h, added only to row ev
#pragma unroll
        for (int reg = 0; reg < 4; ++reg)
          *(uint32_t*)&hTl[w][(4 * g + reg) * 40 + 2 * li] = pk2(hv[0][reg], hv[1][reg]);
        LGKM_FENCE;
        f16x8 ah = *(const f16x8*)&hTl[w][li * 40 + 8 * g];
        f32x4 cj[4];
#pragma unroll
        for (int nt = 0; nt < 4; ++nt) {
          f32x4 c = {jb1v[nt], jb1v[nt], jb1v[nt], jb1v[nt]};
          cj[nt] = MF(ah, WBv[(50 + nt) * 64 + lane], c);
        }
#pragma unroll
        for (int reg = 0; reg < 4; ++reg) {
          uint2 u;
          u.x = pk2(tanh_e(cj[0][reg]), tanh_e(cj[1][reg]));
          u.y = pk2(tanh_e(cj[2][reg]), tanh_e(cj[3][reg]));
          *(uint2*)&actG[w][(4 * g + reg) * 72 + 4 * li] = u;
        }
        LGKM_FENCE;
        f16x8 aj0 = *(const f16x8*)&actG[w][li * 72 + 8 * g];
        f16x8 aj1 = *(const f16x8*)&actG[w][li * 72 + 32 + 8 * g];
        f32x4 jm[2];
#pragma unroll
        for (int nt = 0; nt < 2; ++nt) {
          f32x4 c = {jb2v[nt], jb2v[nt], jb2v[nt], jb2v[nt]};
          c = MF(aj0, WBv[(54 + nt) * 64 + lane], c);
          jm[nt] = MF(aj1, WBv[(56 + nt) * 64 + lane], c);
        }
#pragma unroll
        for (int reg = 0; reg < 4; ++reg)
          if (w * 16 + 4 * g + reg == ev) {
            hv[0][reg] += jm[0][reg];
            hv[1][reg] += jm[1][reg];
          }
      }
#pragma unroll
      for (int reg = 0; reg < 4; ++reg)
        *(uint32_t*)&hTl[w][(4 * g + reg) * 40 + 2 * li] = pk2(hv[0][reg], hv[1][reg]);
      LGKM_FENCE;
    }

    // ---- interval (round-7 step math verbatim; w3/e weights from LDS) ----
    const float t0 = time_[b * S_ + s - 1], t1 = time_[b * S_ + s];
    const float dt = (t1 - t0) / 10.0f;
    const float sq = sqrtf(dt);
    const float msk = mask_[b * S_ + s], mskp = mask_[b * S_ + s - 1];

    echain(lprev);                        // l_init (post-msg)
    if (s > 1) {
#pragma unroll
      for (int reg = 0; reg < 4; ++reg)
        accv[reg] += (prevl_r[reg] * mskp + lprev[reg] * msk) * (t0 - prevt_r) * msk;
    }

#pragma unroll 1
    for (int j = 0; j < ND_; ++j) {
      float nz[8];
      noise8(row0, lane, ak.k[(s - 1) * ND_ + j][0], ak.k[(s - 1) * ND_ + j][1], nz);

      const float dft = dt * (float)(j + 1);
      f16x8 ah = *(const f16x8*)&hTl[w][li * 40 + 8 * g];
      f32x4 cf[4], cg[4];
#pragma unroll
      for (int nt = 0; nt < 4; ++nt) {
        f32x4 c = {fb1v[nt], fb1v[nt], fb1v[nt], fb1v[nt]};
        cf[nt] = MF(ah, wl[nt * 64 + lane], c);
        f32x4 d = {gb1v[nt], gb1v[nt], gb1v[nt], gb1v[nt]};
        cg[nt] = MF(ah, wl[(4 + nt) * 64 + lane], d);
      }
      float addf[4], addg[4];
#pragma unroll
      for (int nt = 0; nt < 4; ++nt) {
        addf[nt] = dft * fw32[nt] + t0 * fw33[nt];
        addg[nt] = dft * gw32[nt];
      }
#pragma unroll
      for (int reg = 0; reg < 4; ++reg) {
        uint2 t1v, t2v;
        t1v.x = pk2(tanh_e(cf[0][reg] + addf[0]), tanh_e(cf[1][reg] + addf[1]));
        t1v.y = pk2(tanh_e(cf[2][reg] + addf[2]), tanh_e(cf[3][reg] + addf[3]));
        *(uint2*)&actF[w][(4 * g + reg) * 72 + 4 * li] = t1v;
        t2v.x = pk2(tanh_e(cg[0][reg] + addg[0]), tanh_e(cg[1][reg] + addg[1]));
        t2v.y = pk2(tanh_e(cg[2][reg] + addg[2]), tanh_e(cg[3][reg] + addg[3]));
        *(uint2*)&actG[w][(4 * g + reg) * 72 + 4 * li] = t2v;
      }
      LGKM_FENCE;
      f16x8 af0 = *(const f16x8*)&actF[w][li * 72 + 8 * g];
      f16x8 af1 = *(const f16x8*)&actF[w][li * 72 + 32 + 8 * g];
      f16x8 ag0 = *(const f16x8*)&actG[w][li * 72 + 8 * g];
      f16x8 ag1 = *(const f16x8*)&actG[w][li * 72 + 32 + 8 * g];
#pragma unroll
      for (int nt = 0; nt < 4; ++nt) {
        f32x4 c = {fb2v[nt], fb2v[nt], fb2v[nt], fb2v[nt]};
        c = MF(af0, w2f[2 * nt], c);
        cf[nt] = MF(af1, w2f[2 * nt + 1], c);
        f32x4 d = {gb2v[nt], gb2v[nt], gb2v[nt], gb2v[nt]};
        d = MF(ag0, w2g[2 * nt], d);
        cg[nt] = MF(ag1, w2g[2 * nt + 1], d);
      }
#pragma unroll
      for (int reg = 0; reg < 4; ++reg) {
        uint2 t1v, t2v;
        t1v.x = pk2(tanh_e(cf[0][reg]), tanh_e(cf[1][reg]));
        t1v.y = pk2(tanh_e(cf[2][reg]), tanh_e(cf[3][reg]));
        *(uint2*)&actF[w][(4 * g + reg) * 72 + 4 * li] = t1v;
        t2v.x = pk2(tanh_e(cg[0][reg]), tanh_e(cg[1][reg]));
        t2v.y = pk2(tanh_e(cg[2][reg]), tanh_e(cg[3][reg]));
        *(uint2*)&actG[w][(4 * g + reg) * 72 + 4 * li] = t2v;
      }
      LGKM_FENCE;
      af0 = *(const f16x8*)&actF[w][li * 72 + 8 * g];
      af1 = *(const f16x8*)&actF[w][li * 72 + 32 + 8 * g];
      ag0 = *(const f16x8*)&actG[w][li * 72 + 8 * g];
      ag1 = *(const f16x8*)&actG[w][li * 72 + 32 + 8 * g];
      f32x4 dr[2], di[2];
#pragma unroll
      for (int nt = 0; nt < 2; ++nt) {
        f32x4 c = {fb3v[nt], fb3v[nt], fb3v[nt], fb3v[nt]};
        c = MF(af0, wl[(14 + 2 * nt) * 64 + lane], c);
        dr[nt] = MF(af1, wl[(14 + 2 * nt + 1) * 64 + lane], c);
        f32x4 d = {gb3v[nt], gb3v[nt], gb3v[nt], gb3v[nt]};
        d = MF(ag0, wl[(18 + 2 * nt) * 64 + lane], d);
        di[nt] = MF(ag1, wl[(18 + 2 * nt + 1) * 64 + lane], d);
      }
#pragma unroll
      for (int reg = 0; reg < 4; ++reg) {
        hv[0][reg] += dr[0][reg] * dt + di[0][reg] * sq * nz[reg];
        hv[1][reg] += dr[1][reg] * dt + di[1][reg] * sq * nz[4 + reg];
      }
#pragma unroll
      for (int reg = 0; reg < 4; ++reg)
        *(uint32_t*)&hTl[w][(4 * g + reg) * 40 + 2 * li] = pk2(hv[0][reg], hv[1][reg]);
      LGKM_FENCE;
      float l[4];
      echain(l);
      float tj = t0 + dt * (float)j, tj1 = t0 + dt * (float)(j + 1);
      float dtm = (tj1 - tj) * msk;
#pragma unroll
      for (int reg = 0; reg < 4; ++reg) {
        accv[reg] += (lprev[reg] * msk + l[reg] * msk) * dtm;
        lprev[reg] = l[reg];
      }
    }

    // ---- per-interval epilogue (registers + dout/ltlog) ----
#pragma unroll
    for (int reg = 0; reg < 4; ++reg) prevl_r[reg] = lprev[reg];
    prevt_r = t0 + dt * 10.0f;
    if (li == 0) {
      int evn = type_[b * S_ + s];
#pragma unroll
      for (int reg = 0; reg < 4; ++reg) {
        int v = w * 16 + 4 * g + reg;
        if (v < V_) {
          dout[1 + (b * S_ + s) * V_ + v] = lprev[reg];
          if (v == evn) ltlog[s * B_ + b] = logf(lprev[reg] + 1e-16f) * msk;
        }
      }
    }
  }

  // ---- final: store acc ----
  if (li == 0) {
#pragma unroll
    for (int reg = 0; reg < 4; ++reg) {
      int v = w * 16 + 4 * g + reg;
      if (v < V_) acc[b * V_ + v] = accv[reg];
    }
  }
}

// ---------------- deterministic final reduce ----------------
__global__ void reduce_k(const float* __restrict__ acc, const float* __restrict__ ltlog,
                         float* __restrict__ dout) {
  __shared__ double sh[512];
  int t = threadIdx.x;
  double ia = 0.0, st = 0.0;
  for (int i = t; i < NROW; i += 256) ia += (double)acc[i];
  for (int i = t; i < B_ * S_; i += 256) st += (double)ltlog[i];
  sh[t] = ia; sh[256 + t] = st;
  __syncthreads();
  for (int o = 128; o > 0; o >>= 1) {
    if (t < o) { sh[t] += sh[t + o]; sh[256 + t] += sh[256 + t + o]; }
    __syncthreads();
  }
  if (t == 0) dout[0] = (float)(0.5 * sh[0] - sh[256]);
}

extern "C" void kernel_launch(void* const* d_in, const int* in_sizes, int n_in,
                              void* d_out, int out_size, void* d_ws, size_t ws_size,
                              hipStream_t stream) {
  const float* time_  = (const float*)d_in[0];
  const int*   type_  = (const int*)d_in[1];
  const float* mask_  = (const float*)d_in[2];
  const float* logits = (const float*)d_in[3];
  const float* h0     = (const float*)d_in[4];
  const float* fW1 = (const float*)d_in[5];  const float* fb1 = (const float*)d_in[6];
  const float* fW2 = (const float*)d_in[7];  const float* fb2 = (const float*)d_in[8];
  const float* fW3 = (const float*)d_in[9];  const float* fb3 = (const float*)d_in[10];
  const float* gW1 = (const float*)d_in[11]; const float* gb1 = (const float*)d_in[12];
  const float* gW2 = (const float*)d_in[13]; const float* gb2 = (const float*)d_in[14];
  const float* gW3 = (const float*)d_in[15]; const float* gb3 = (const float*)d_in[16];
  const float* eW1 = (const float*)d_in[17]; const float* eb1 = (const float*)d_in[18];
  const float* eW2 = (const float*)d_in[19]; const float* eb2 = (const float*)d_in[20];
  const float* jW1 = (const float*)d_in[21]; const float* jb1 = (const float*)d_in[22];
  const float* jW2 = (const float*)d_in[23]; const float* jb2 = (const float*)d_in[24];
  const float* mW1 = (const float*)d_in[25]; const float* mb1 = (const float*)d_in[26];
  const float* mW2 = (const float*)d_in[27]; const float* mb2 = (const float*)d_in[28];
  float* out = (float*)d_out;

  float* ws    = (float*)d_ws;
  float* acc   = ws + WO_ACC;
  float* ltlog = ws + WO_LTLOG;

  // host-side key chain: key(42); 310x fold-like split (verified bit-exact)
  uint32_t kh = 0u, kl = 42u;
  AllK ak;
  for (int n = 0; n < 310; ++n) {
    uint32_t a0 = 0u, a1 = 0u; tf2x32(kh, kl, a0, a1);
    uint32_t b0 = 0u, b1 = 1u; tf2x32(kh, kl, b0, b1);
    ak.k[n][0] = b0; ak.k[n][1] = b1;
    kh = a0; kl = a1;
  }

  prep_k<<<54, 256, 0, stream>>>(fW1, gW1, fW2, gW2, fW3, gW3, eW1, eW2,
                                 mW1, mW2, jW1, jW2, logits, ws);
  chain_k<<<B_, 448, 0, stream>>>(time_, type_, mask_, ws,
                                  fb1, fb2, fb3, gb1, gb2, gb3, eb1, eb2,
                                  fW1, gW1, mb1, mb2, jb1, jb2, h0,
                                  acc, ltlog, out, ak);
  reduce_k<<<1, 256, 0, stream>>>(acc, ltlog, out);
}

// Round 9
// 1118.813 us; speedup vs baseline: 2.7402x; 2.7402x over previous
//
#include <hip/hip_runtime.h>
#include <hip/hip_fp16.h>
#include <stdint.h>

#define B_  32
#define S_  32
#define V_  100
#define HD_ 32
#define HID_ 64
#define ND_ 10
#define NROW (B_*V_)
#define NTILE 7
#define NBLK (B_*NTILE)   // 224 blocks
#define NFRAG 58

// ---- workspace float offsets ----
#define WO_EP    14848                          // 58 frags * 64 * 4 floats before this
#define WO_HA    24848
#define WO_HB    127248
#define WO_ACC   229648
#define WO_PREVL 232848
#define WO_PREVT 236048
#define WO_LTLOG 239248
#define WO_NOISE 240272
#define NOISE_FLOATS ((size_t)310 * NBLK * 64 * 8)

typedef __attribute__((ext_vector_type(8))) _Float16 f16x8;
typedef __attribute__((ext_vector_type(4))) float f32x4;

#define LGKM_FENCE asm volatile("s_waitcnt lgkmcnt(0)" ::: "memory")

// ---------------- threefry2x32 (JAX-compatible, verified) ----------------
__host__ __device__ inline void tf2x32(uint32_t k0, uint32_t k1,
                                       uint32_t& x0, uint32_t& x1) {
  uint32_t ks0 = k0, ks1 = k1, ks2 = k0 ^ k1 ^ 0x1BD11BDAu;
#define TFR(r) { x0 += x1; x1 = (x1 << (r)) | (x1 >> (32 - (r))); x1 ^= x0; }
  x0 += ks0; x1 += ks1;
  TFR(13) TFR(15) TFR(26) TFR(6)
  x0 += ks1; x1 += ks2 + 1u;
  TFR(17) TFR(29) TFR(16) TFR(24)
  x0 += ks2; x1 += ks0 + 2u;
  TFR(13) TFR(15) TFR(26) TFR(6)
  x0 += ks0; x1 += ks1 + 3u;
  TFR(17) TFR(29) TFR(16) TFR(24)
  x0 += ks1; x1 += ks2 + 4u;
  TFR(13) TFR(15) TFR(26) TFR(6)
  x0 += ks2; x1 += ks0 + 5u;
#undef TFR
}

// ---------------- erfinv (XLA / Giles f32 polynomial) ----------------
__device__ __forceinline__ float erfinv_f(float x) {
  float w = -log1pf(-x * x);
  float p;
  if (w < 5.0f) {
    w -= 2.5f;
    p = 2.81022636e-08f;
    p = fmaf(p, w, 3.43273939e-07f);
    p = fmaf(p, w, -3.5233877e-06f);
    p = fmaf(p, w, -4.39150654e-06f);
    p = fmaf(p, w, 0.00021858087f);
    p = fmaf(p, w, -0.00125372503f);
    p = fmaf(p, w, -0.00417768164f);
    p = fmaf(p, w, 0.246640727f);
    p = fmaf(p, w, 1.50140941f);
  } else {
    w = sqrtf(w) - 3.0f;
    p = -0.000200214257f;
    p = fmaf(p, w, 0.000100950558f);
    p = fmaf(p, w, 0.00134934322f);
    p = fmaf(p, w, -0.00367342844f);
    p = fmaf(p, w, 0.00573950773f);
    p = fmaf(p, w, -0.0076224613f);
    p = fmaf(p, w, 0.00943887047f);
    p = fmaf(p, w, 1.00167406f);
    p = fmaf(p, w, 2.83297682f);
  }
  return p * x;
}

// ---------------- fast device math ----------------
__device__ __forceinline__ float tanh_e(float x) {
  float e = __builtin_amdgcn_exp2f(x * 2.885390082f);
  return 1.0f - 2.0f * __builtin_amdgcn_rcpf(e + 1.0f);
}
__device__ __forceinline__ float softplus_fast(float x) {
  return fmaxf(x, 0.0f) + __logf(1.0f + __expf(-fabsf(x)));
}
__device__ __forceinline__ unsigned short f16b(float x) {
  __half h = __float2half(x);
  return *reinterpret_cast<unsigned short*>(&h);
}
__device__ __forceinline__ uint32_t pk2(float a, float b) {
  return (uint32_t)f16b(a) | ((uint32_t)f16b(b) << 16);
}
__device__ __forceinline__ f32x4 MF(f16x8 a, f16x8 b, f32x4 c) {
  return __builtin_amdgcn_mfma_f32_16x16x32_f16(a, b, c, 0, 0, 0);
}

struct SubK { uint32_t k[ND_][2]; };
struct AllK { uint32_t k[310][2]; };

// noise values for one wave-lane: v = t*4+reg -> (row = row0+4g+reg, dim = li+16t)
__device__ __forceinline__ void noise8(int row0, int lane, uint32_t k0, uint32_t k1,
                                       float* n) {
  int g = lane >> 4, li = lane & 15;
#pragma unroll
  for (int v = 0; v < 8; ++v) {
    int reg = v & 3, t = v >> 2;
    int row = row0 + 4 * g + reg;
    uint32_t x0 = 0u, x1 = (uint32_t)(row * HD_ + li + 16 * t);
    tf2x32(k0, k1, x0, x1);
    uint32_t bits = x0 ^ x1;
    float fr = __uint_as_float(0x3f800000u | (bits >> 9)) - 1.0f;
    const float LOW = -0.99999994f;
    float u = fmaxf(LOW, fr * 2.0f + LOW);
    n[v] = 1.4142135f * erfinv_f(u);
  }
}

// ---------------- prep: 58 f16 MFMA B-fragments + edge_prob (round-8 verified) ----------------
__global__ void prep_k(const float* __restrict__ fW1, const float* __restrict__ gW1,
                       const float* __restrict__ fW2, const float* __restrict__ gW2,
                       const float* __restrict__ fW3, const float* __restrict__ gW3,
                       const float* __restrict__ eW1, const float* __restrict__ eW2,
                       const float* __restrict__ mW1, const float* __restrict__ mW2,
                       const float* __restrict__ jW1, const float* __restrict__ jW2,
                       const float* __restrict__ logits, float* __restrict__ ws) {
  int tid = blockIdx.x * 256 + threadIdx.x;
  if (tid < NFRAG * 64) {
    int fid = tid >> 6, lane = tid & 63;
    int g = lane >> 4, li = lane & 15;
    const float* src; int k0 = 0, n0 = 0, ncol = HID_; bool hperm = false, col0 = false;
    if (fid < 4)       { src = fW1; n0 = 16 * fid;       hperm = true; }
    else if (fid < 8)  { src = gW1; n0 = 16 * (fid - 4); hperm = true; }
    else if (fid < 16) { int q = fid - 8;  src = fW2; n0 = 16 * (q >> 1); k0 = 32 * (q & 1); }
    else if (fid < 24) { int q = fid - 16; src = gW2; n0 = 16 * (q >> 1); k0 = 32 * (q & 1); }
    else if (fid < 28) { int q = fid - 24; src = fW3; n0 = 16 * (q >> 1); k0 = 32 * (q & 1); ncol = HD_; }
    else if (fid < 32) { int q = fid - 28; src = gW3; n0 = 16 * (q >> 1); k0 = 32 * (q & 1); ncol = HD_; }
    else if (fid < 36) { src = eW1; n0 = 16 * (fid - 32); hperm = true; }
    else if (fid < 38) { src = eW2; k0 = 32 * (fid - 36); col0 = true; }
    else if (fid < 46) { int q = fid - 38; src = mW1; k0 = 32 * (q >> 2); n0 = 16 * (q & 3); hperm = true; }
    else if (fid < 50) { int q = fid - 46; src = mW2; k0 = 32 * (q >> 1); n0 = 16 * (q & 1); ncol = HD_; }
    else if (fid < 54) { src = jW1; n0 = 16 * (fid - 50); hperm = true; }
    else               { int q = fid - 54; src = jW2; k0 = 32 * (q >> 1); n0 = 16 * (q & 1); ncol = HD_; }
    unsigned short v[8];
#pragma unroll
    for (int j = 0; j < 8; ++j) {
      int sl = 8 * g + j;
      int k;
      if (hperm) k = k0 + ((sl >> 1) + 16 * (sl & 1));
      else { int s2 = k0 + sl; k = (s2 >> 2) + 16 * (s2 & 3); }
      float x;
      if (col0) x = (li == 0) ? src[k] : 0.0f;
      else      x = src[k * ncol + (n0 + li)];
      v[j] = f16b(x);
    }
    uint4 o;
    o.x = (uint32_t)v[0] | ((uint32_t)v[1] << 16);
    o.y = (uint32_t)v[2] | ((uint32_t)v[3] << 16);
    o.z = (uint32_t)v[4] | ((uint32_t)v[5] << 16);
    o.w = (uint32_t)v[6] | ((uint32_t)v[7] << 16);
    ((uint4*)ws)[fid * 64 + lane] = o;
  } else if (tid < NFRAG * 64 + V_ * V_) {
    int idx = tid - NFRAG * 64;
    float l0v = logits[idx], l1v = logits[V_ * V_ + idx];
    float mx = fmaxf(l0v, l1v);
    float e0 = expf(l0v - mx), e1 = expf(l1v - mx);
    ws[WO_EP + idx] = e1 / (e0 + e1);
  }
}

// ---------------- noise precompute (round-5 verified) ----------------
__global__ void noise_k(float* __restrict__ np, AllK ak) {
  int pair = blockIdx.x * 4 + (threadIdx.x >> 6);   // (sg, bid)
  int lane = threadIdx.x & 63;
  int sg = pair / NBLK, bid = pair - sg * NBLK;
  int b = bid / NTILE, tile = bid - b * NTILE;
  int row0 = b * V_ + tile * 16;
  float n[8];
  noise8(row0, lane, ak.k[sg][0], ak.k[sg][1], n);
  float* dst = np + ((size_t)pair * 64 + lane) * 8;
  f32x4 a = {n[0], n[1], n[2], n[3]}, c = {n[4], n[5], n[6], n[7]};
  ((f32x4*)dst)[0] = a;
  ((f32x4*)dst)[1] = c;
}

// used by init_k only
template<int K4, int O>
__device__ __forceinline__ float dotWxT(const float* __restrict__ W,
                                        const float* __restrict__ x,
                                        float a, int lane) {
#pragma unroll
  for (int kb = 0; kb < K4; ++kb) {
    float4 xv = *(const float4*)(x + kb * 4);
    a = fmaf(xv.x, W[(kb * 4 + 0) * O + lane], a);
    a = fmaf(xv.y, W[(kb * 4 + 1) * O + lane], a);
    a = fmaf(xv.z, W[(kb * 4 + 2) * O + lane], a);
    a = fmaf(xv.w, W[(kb * 4 + 3) * O + lane], a);
  }
  return a;
}

// ---------------- init: hA = broadcast(h0); l0; lt0; acc=0 ----------------
__launch_bounds__(256)
__global__ void init_k(const int* __restrict__ type_, const float* __restrict__ mask_,
                       const float* __restrict__ h0,
                       const float* __restrict__ eW1, const float* __restrict__ eb1,
                       const float* __restrict__ eW2, const float* __restrict__ eb2,
                       float* __restrict__ hA, float* __restrict__ acc,
                       float* __restrict__ ltlog, float* __restrict__ dout) {
  __shared__ float xls[4][64];
  const int w = threadIdx.x >> 6, lane = threadIdx.x & 63;
  const int row = blockIdx.x * 4 + w;
  const int b = row / V_, v = row - b * V_;
  if (lane < 32) {
    float x = h0[v * HD_ + lane];
    xls[w][lane] = x;
    hA[row * HD_ + lane] = x;
  }
  float a = dotWxT<8, 64>(eW1, xls[w], eb1[lane], lane);
  float t = tanhf(a) * eW2[lane];
#pragma unroll
  for (int o = 1; o < 64; o <<= 1) t += __shfl_xor(t, o, 64);
  float z = t + eb2[0];
  float l0 = fmaxf(z, 0.0f) + log1pf(expf(-fabsf(z)));
  if (lane == 0) {
    dout[1 + (b * S_ + 0) * V_ + v] = l0;
    acc[row] = 0.0f;
    if (v == type_[b * S_]) ltlog[b] = logf(l0 + 1e-16f) * mask_[b * S_];
  }
}

// ---------------- fused euler: msg_jump(ev_{s-1}) + 10 SDE steps ----------------
__launch_bounds__(64, 1)
__global__ void euler_k(const float* __restrict__ time_, const int* __restrict__ type_,
                        const float* __restrict__ mask_, const float* __restrict__ wsf,
                        const float* __restrict__ fb1, const float* __restrict__ fb2,
                        const float* __restrict__ fb3, const float* __restrict__ gb1,
                        const float* __restrict__ gb2, const float* __restrict__ gb3,
                        const float* __restrict__ eb1, const float* __restrict__ eb2,
                        const float* __restrict__ eW2, const float* __restrict__ fW1,
                        const float* __restrict__ gW1,
                        const float* __restrict__ mb1, const float* __restrict__ mb2,
                        const float* __restrict__ jb1, const float* __restrict__ jb2,
                        const float* __restrict__ hsrc, float* __restrict__ hdst,
                        float* __restrict__ acc, float* __restrict__ prevl,
                        float* __restrict__ prevt, float* __restrict__ ltlog,
                        float* __restrict__ dout,
                        const float* __restrict__ nin, int s, SubK skc) {
  __shared__ unsigned short actF[16 * 72];
  __shared__ unsigned short actG[16 * 72];
  __shared__ unsigned short hTl[16 * 40];
  __shared__ f16x8 wl[12 * 64];              // L1f 0-3, L1g 4-7, e1 8-11

  const int lane = threadIdx.x;
  const int g = lane >> 4, li = lane & 15;
  const int bid = blockIdx.x;
  const int b = bid / NTILE, tile = bid - b * NTILE;
  const int row0 = b * V_ + tile * 16;
  const int rmax = b * V_ + (V_ - 1);
  const int ev = type_[b * S_ + s - 1];

  const f16x8* WBv = (const f16x8*)wsf;
  const float* ep = wsf + WO_EP;

  // stage L1 + e1 fragments to LDS
#pragma unroll
  for (int i = 0; i < 8; ++i) wl[i * 64 + lane] = WBv[i * 64 + lane];
#pragma unroll
  for (int i = 0; i < 4; ++i) wl[(8 + i) * 64 + lane] = WBv[(32 + i) * 64 + lane];

  // register weights: L2 (w2f,w2g), L3 (w3f,w3g)
  f16x8 w2f[8], w2g[8], w3f[4], w3g[4];
#pragma unroll
  for (int i = 0; i < 8; ++i) w2f[i] = WBv[(8 + i) * 64 + lane];
#pragma unroll
  for (int i = 0; i < 8; ++i) w2g[i] = WBv[(16 + i) * 64 + lane];
#pragma unroll
  for (int i = 0; i < 4; ++i) w3f[i] = WBv[(24 + i) * 64 + lane];
#pragma unroll
  for (int i = 0; i < 4; ++i) w3g[i] = WBv[(28 + i) * 64 + lane];

  float fb1v[4], gb1v[4], fb2v[4], gb2v[4], eb1v[4], e2v[4], fw32[4], fw33[4], gw32[4];
  float mb1v[4], jb1v[4];
#pragma unroll
  for (int nt = 0; nt < 4; ++nt) {
    int n = li + 16 * nt;
    fb1v[nt] = fb1[n]; gb1v[nt] = gb1[n];
    fb2v[nt] = fb2[n]; gb2v[nt] = gb2[n];
    eb1v[nt] = eb1[n]; e2v[nt] = eW2[n];
    fw32[nt] = fW1[32 * HID_ + n]; fw33[nt] = fW1[33 * HID_ + n];
    gw32[nt] = gW1[32 * HID_ + n];
    mb1v[nt] = mb1[n]; jb1v[nt] = jb1[n];
  }
  float fb3v[2], gb3v[2], mb2v[2], jb2v[2];
#pragma unroll
  for (int nt = 0; nt < 2; ++nt) {
    fb3v[nt] = fb3[li + 16 * nt]; gb3v[nt] = gb3[li + 16 * nt];
    mb2v[nt] = mb2[li + 16 * nt]; jb2v[nt] = jb2[li + 16 * nt];
  }
  const float eb2v = eb2[0];

  const float t0 = time_[b * S_ + s - 1], t1 = time_[b * S_ + s];
  const float dt = (t1 - t0) / 10.0f;
  const float sq = sqrtf(dt);
  const float msk = mask_[b * S_ + s], mskp = mask_[b * S_ + s - 1];

  // own h rows (pre-msg, f32)
  float hv[2][4];
#pragma unroll
  for (int t = 0; t < 2; ++t)
#pragma unroll
    for (int reg = 0; reg < 4; ++reg) {
      int rv = row0 + 4 * g + reg; if (rv > rmax) rv = rmax;
      hv[t][reg] = hsrc[rv * HD_ + li + 16 * t];
    }

  // ================= msg phase (round-8 verified MFMA form) =================
  {
    float sd0 = hsrc[(b * V_ + ev) * HD_ + li];
    float sd1 = hsrc[(b * V_ + ev) * HD_ + li + 16];
    uint32_t su = pk2(sd0, sd1);
#pragma unroll
    for (int reg = 0; reg < 4; ++reg) {
      *(uint32_t*)&actF[(4 * g + reg) * 72 + 2 * li] = su;                       // send (h-perm)
      *(uint32_t*)&actG[(4 * g + reg) * 72 + 2 * li] = pk2(hv[0][reg], hv[1][reg]); // own
    }
    LGKM_FENCE;
    f16x8 ap0 = *(const f16x8*)&actF[li * 72 + 8 * g];
    f16x8 ap1 = *(const f16x8*)&actG[li * 72 + 8 * g];
    f32x4 cm[4];
#pragma unroll
    for (int nt = 0; nt < 4; ++nt) {
      f32x4 c = {mb1v[nt], mb1v[nt], mb1v[nt], mb1v[nt]};
      c = MF(ap0, WBv[(38 + nt) * 64 + lane], c);
      cm[nt] = MF(ap1, WBv[(42 + nt) * 64 + lane], c);
    }
#pragma unroll
    for (int reg = 0; reg < 4; ++reg) {
      uint2 u;
      u.x = pk2(tanh_e(cm[0][reg]), tanh_e(cm[1][reg]));
      u.y = pk2(tanh_e(cm[2][reg]), tanh_e(cm[3][reg]));
      *(uint2*)&actF[(4 * g + reg) * 72 + 4 * li] = u;
    }
    LGKM_FENCE;
    f16x8 am0 = *(const f16x8*)&actF[li * 72 + 8 * g];
    f16x8 am1 = *(const f16x8*)&actF[li * 72 + 32 + 8 * g];
    f32x4 mm[2];
#pragma unroll
    for (int nt = 0; nt < 2; ++nt) {
      f32x4 c = {mb2v[nt], mb2v[nt], mb2v[nt], mb2v[nt]};
      c = MF(am0, WBv[(46 + nt) * 64 + lane], c);
      mm[nt] = MF(am1, WBv[(48 + nt) * 64 + lane], c);
    }
#pragma unroll
    for (int reg = 0; reg < 4; ++reg) {
      int v = tile * 16 + 4 * g + reg; int vc = (v < V_) ? v : (V_ - 1);
      float p = ep[ev * V_ + vc];
      hv[0][reg] += mm[0][reg] * p;
      hv[1][reg] += mm[1][reg] * p;
    }
    if (tile == (ev >> 4)) {              // block-uniform: jump for row ev
#pragma unroll
      for (int reg = 0; reg < 4; ++reg)
        *(uint32_t*)&hTl[(4 * g + reg) * 40 + 2 * li] = pk2(hv[0][reg], hv[1][reg]);
      LGKM_FENCE;
      f16x8 ah = *(const f16x8*)&hTl[li * 40 + 8 * g];
      f32x4 cj[4];
#pragma unroll
      for (int nt = 0; nt < 4; ++nt) {
        f32x4 c = {jb1v[nt], jb1v[nt], jb1v[nt], jb1v[nt]};
        cj[nt] = MF(ah, WBv[(50 + nt) * 64 + lane], c);
      }
#pragma unroll
      for (int reg = 0; reg < 4; ++reg) {
        uint2 u;
        u.x = pk2(tanh_e(cj[0][reg]), tanh_e(cj[1][reg]));
        u.y = pk2(tanh_e(cj[2][reg]), tanh_e(cj[3][reg]));
        *(uint2*)&actG[(4 * g + reg) * 72 + 4 * li] = u;
      }
      LGKM_FENCE;
      f16x8 aj0 = *(const f16x8*)&actG[li * 72 + 8 * g];
      f16x8 aj1 = *(const f16x8*)&actG[li * 72 + 32 + 8 * g];
      f32x4 jm[2];
#pragma unroll
      for (int nt = 0; nt < 2; ++nt) {
        f32x4 c = {jb2v[nt], jb2v[nt], jb2v[nt], jb2v[nt]};
        c = MF(aj0, WBv[(54 + nt) * 64 + lane], c);
        jm[nt] = MF(aj1, WBv[(56 + nt) * 64 + lane], c);
      }
#pragma unroll
      for (int reg = 0; reg < 4; ++reg)
        if (tile * 16 + 4 * g + reg == ev) {
          hv[0][reg] += jm[0][reg];
          hv[1][reg] += jm[1][reg];
        }
    }
#pragma unroll
    for (int reg = 0; reg < 4; ++reg)
      *(uint32_t*)&hTl[(4 * g + reg) * 40 + 2 * li] = pk2(hv[0][reg], hv[1][reg]);
    LGKM_FENCE;
  }

  float accv[4], lprev[4], plv[4];
#pragma unroll
  for (int reg = 0; reg < 4; ++reg) {
    int rv = row0 + 4 * g + reg; if (rv > rmax) rv = rmax;
    accv[reg] = acc[rv];
    plv[reg] = (s > 1) ? prevl[rv] : 0.0f;
  }
  const float ptv = (s > 1) ? prevt[row0] : 0.0f;

  // e-finish: given e1 accumulators (f32), produce l per row via shfl reduce
  auto efin = [&](f32x4* ce, float* lout) {
#pragma unroll
    for (int reg = 0; reg < 4; ++reg) {
      float p = tanh_e(ce[0][reg]) * e2v[0];
      p = fmaf(tanh_e(ce[1][reg]), e2v[1], p);
      p = fmaf(tanh_e(ce[2][reg]), e2v[2], p);
      p = fmaf(tanh_e(ce[3][reg]), e2v[3], p);
#pragma unroll
      for (int m = 1; m < 16; m <<= 1) p += __shfl_xor(p, m, 64);
      lout[reg] = softplus_fast(p + eb2v);
    }
  };

  // ================= merged main loop =================
#pragma unroll 1
  for (int j = 0; j < ND_; ++j) {
    f32x4 q0, q1;
    if (nin) {
      const float* qp = nin + ((size_t)(j * NBLK + bid) * 64 + lane) * 8;
      q0 = ((const f32x4*)qp)[0]; q1 = ((const f32x4*)qp)[1];
    } else {
      float n[8];
      noise8(row0, lane, skc.k[j][0], skc.k[j][1], n);
      q0 = {n[0], n[1], n[2], n[3]}; q1 = {n[4], n[5], n[6], n[7]};
    }

    f16x8 ah = *(const f16x8*)&hTl[li * 40 + 8 * g];
    // ---- group 1: f1 + g1 + e1 (shared A-frag) ----
    f32x4 cf[4], cg[4], ce[4];
#pragma unroll
    for (int nt = 0; nt < 4; ++nt) {
      f32x4 c0 = {fb1v[nt], fb1v[nt], fb1v[nt], fb1v[nt]};
      cf[nt] = MF(ah, wl[nt * 64 + lane], c0);
      f32x4 c1 = {gb1v[nt], gb1v[nt], gb1v[nt], gb1v[nt]};
      cg[nt] = MF(ah, wl[(4 + nt) * 64 + lane], c1);
      f32x4 c2 = {eb1v[nt], eb1v[nt], eb1v[nt], eb1v[nt]};
      ce[nt] = MF(ah, wl[(8 + nt) * 64 + lane], c2);
    }
    const float dft = dt * (float)(j + 1);
    float addf[4], addg[4];
#pragma unroll
    for (int nt = 0; nt < 4; ++nt) {
      addf[nt] = dft * fw32[nt] + t0 * fw33[nt];
      addg[nt] = dft * gw32[nt];
    }
#pragma unroll
    for (int reg = 0; reg < 4; ++reg) {
      uint2 uf, ug;
      uf.x = pk2(tanh_e(cf[0][reg] + addf[0]), tanh_e(cf[1][reg] + addf[1]));
      uf.y = pk2(tanh_e(cf[2][reg] + addf[2]), tanh_e(cf[3][reg] + addf[3]));
      *(uint2*)&actF[(4 * g + reg) * 72 + 4 * li] = uf;
      ug.x = pk2(tanh_e(cg[0][reg] + addg[0]), tanh_e(cg[1][reg] + addg[1]));
      ug.y = pk2(tanh_e(cg[2][reg] + addg[2]), tanh_e(cg[3][reg] + addg[3]));
      *(uint2*)&actG[(4 * g + reg) * 72 + 4 * li] = ug;
    }
    // e-net finish in-register (overlaps with LDS writes)
    float lc[4];
    efin(ce, lc);       // lc = l(h_j)
    if (j == 0) {
      if (s > 1) {
#pragma unroll
        for (int reg = 0; reg < 4; ++reg)
          accv[reg] += (plv[reg] * mskp + lc[reg] * msk) * (t0 - ptv) * msk;
      }
    } else {
      float dtm = dt * msk;
#pragma unroll
      for (int reg = 0; reg < 4; ++reg)
        accv[reg] += (lprev[reg] * msk + lc[reg] * msk) * dtm;
    }
#pragma unroll
    for (int reg = 0; reg < 4; ++reg) lprev[reg] = lc[reg];
    LGKM_FENCE;
    // ---- group 2: L2 ----
    f16x8 af0 = *(const f16x8*)&actF[li * 72 + 8 * g];
    f16x8 af1 = *(const f16x8*)&actF[li * 72 + 32 + 8 * g];
    f16x8 ag0 = *(const f16x8*)&actG[li * 72 + 8 * g];
    f16x8 ag1 = *(const f16x8*)&actG[li * 72 + 32 + 8 * g];
#pragma unroll
    for (int nt = 0; nt < 4; ++nt) {
      f32x4 c = {fb2v[nt], fb2v[nt], fb2v[nt], fb2v[nt]};
      c = MF(af0, w2f[2 * nt], c);
      cf[nt] = MF(af1, w2f[2 * nt + 1], c);
      f32x4 d = {gb2v[nt], gb2v[nt], gb2v[nt], gb2v[nt]};
      d = MF(ag0, w2g[2 * nt], d);
      cg[nt] = MF(ag1, w2g[2 * nt + 1], d);
    }
#pragma unroll
    for (int reg = 0; reg < 4; ++reg) {
      uint2 uf, ug;
      uf.x = pk2(tanh_e(cf[0][reg]), tanh_e(cf[1][reg]));
      uf.y = pk2(tanh_e(cf[2][reg]), tanh_e(cf[3][reg]));
      *(uint2*)&actF[(4 * g + reg) * 72 + 4 * li] = uf;
      ug.x = pk2(tanh_e(cg[0][reg]), tanh_e(cg[1][reg]));
      ug.y = pk2(tanh_e(cg[2][reg]), tanh_e(cg[3][reg]));
      *(uint2*)&actG[(4 * g + reg) * 72 + 4 * li] = ug;
    }
    LGKM_FENCE;
    // ---- group 3: L3 -> drift/diff; h update ----
    af0 = *(const f16x8*)&actF[li * 72 + 8 * g];
    af1 = *(const f16x8*)&actF[li * 72 + 32 + 8 * g];
    ag0 = *(const f16x8*)&actG[li * 72 + 8 * g];
    ag1 = *(const f16x8*)&actG[li * 72 + 32 + 8 * g];
    f32x4 dr[2], di[2];
#pragma unroll
    for (int nt = 0; nt < 2; ++nt) {
      f32x4 c = {fb3v[nt], fb3v[nt], fb3v[nt], fb3v[nt]};
      c = MF(af0, w3f[2 * nt], c);
      dr[nt] = MF(af1, w3f[2 * nt + 1], c);
      f32x4 d = {gb3v[nt], gb3v[nt], gb3v[nt], gb3v[nt]};
      d = MF(ag0, w3g[2 * nt], d);
      di[nt] = MF(ag1, w3g[2 * nt + 1], d);
    }
#pragma unroll
    for (int reg = 0; reg < 4; ++reg) {
      hv[0][reg] += dr[0][reg] * dt + di[0][reg] * sq * q0[reg];
      hv[1][reg] += dr[1][reg] * dt + di[1][reg] * sq * q1[reg];
    }
#pragma unroll
    for (int reg = 0; reg < 4; ++reg)
      *(uint32_t*)&hTl[(4 * g + reg) * 40 + 2 * li] = pk2(hv[0][reg], hv[1][reg]);
    LGKM_FENCE;
  }

  // ================= epilogue: l(h_10) =================
  float llast[4];
  {
    f16x8 ah = *(const f16x8*)&hTl[li * 40 + 8 * g];
    f32x4 ce[4];
#pragma unroll
    for (int nt = 0; nt < 4; ++nt) {
      f32x4 c = {eb1v[nt], eb1v[nt], eb1v[nt], eb1v[nt]};
      ce[nt] = MF(ah, wl[(8 + nt) * 64 + lane], c);
    }
    efin(ce, llast);
    float dtm = dt * msk;
#pragma unroll
    for (int reg = 0; reg < 4; ++reg)
      accv[reg] += (lprev[reg] * msk + llast[reg] * msk) * dtm;
  }

  // ---- stores (guard padded rows) ----
#pragma unroll
  for (int t = 0; t < 2; ++t)
#pragma unroll
    for (int reg = 0; reg < 4; ++reg) {
      int v = tile * 16 + 4 * g + reg;
      if (v < V_) hdst[(row0 + 4 * g + reg) * HD_ + li + 16 * t] = hv[t][reg];
    }
  if (li == 0) {
    int evn = type_[b * S_ + s];
    float pt = t0 + dt * 10.0f;
#pragma unroll
    for (int reg = 0; reg < 4; ++reg) {
      int v = tile * 16 + 4 * g + reg;
      if (v < V_) {
        int rv = row0 + 4 * g + reg;
        acc[rv] = accv[reg];
        prevl[rv] = llast[reg];
        prevt[rv] = pt;
        dout[1 + (b * S_ + s) * V_ + v] = llast[reg];
        if (v == evn) ltlog[s * B_ + b] = logf(llast[reg] + 1e-16f) * msk;
      }
    }
  }
}

// ---------------- deterministic final reduce ----------------
__global__ void reduce_k(const float* __restrict__ acc, const float* __restrict__ ltlog,
                         float* __restrict__ dout) {
  __shared__ double sh[512];
  int t = threadIdx.x;
  double ia = 0.0, st = 0.0;
  for (int i = t; i < NROW; i += 256) ia += (double)acc[i];
  for (int i = t; i < B_ * S_; i += 256) st += (double)ltlog[i];
  sh[t] = ia; sh[256 + t] = st;
  __syncthreads();
  for (int o = 128; o > 0; o >>= 1) {
    if (t < o) { sh[t] += sh[t + o]; sh[256 + t] += sh[256 + t + o]; }
    __syncthreads();
  }
  if (t == 0) dout[0] = (float)(0.5 * sh[0] - sh[256]);
}

extern "C" void kernel_launch(void* const* d_in, const int* in_sizes, int n_in,
                              void* d_out, int out_size, void* d_ws, size_t ws_size,
                              hipStream_t stream) {
  const float* time_  = (const float*)d_in[0];
  const int*   type_  = (const int*)d_in[1];
  const float* mask_  = (const float*)d_in[2];
  const float* logits = (const float*)d_in[3];
  const float* h0     = (const float*)d_in[4];
  const float* fW1 = (const float*)d_in[5];  const float* fb1 = (const float*)d_in[6];
  const float* fW2 = (const float*)d_in[7];  const float* fb2 = (const float*)d_in[8];
  const float* fW3 = (const float*)d_in[9];  const float* fb3 = (const float*)d_in[10];
  const float* gW1 = (const float*)d_in[11]; const float* gb1 = (const float*)d_in[12];
  const float* gW2 = (const float*)d_in[13]; const float* gb2 = (const float*)d_in[14];
  const float* gW3 = (const float*)d_in[15]; const float* gb3 = (const float*)d_in[16];
  const float* eW1 = (const float*)d_in[17]; const float* eb1 = (const float*)d_in[18];
  const float* eW2 = (const float*)d_in[19]; const float* eb2 = (const float*)d_in[20];
  const float* jW1 = (const float*)d_in[21]; const float* jb1 = (const float*)d_in[22];
  const float* jW2 = (const float*)d_in[23]; const float* jb2 = (const float*)d_in[24];
  const float* mW1 = (const float*)d_in[25]; const float* mb1 = (const float*)d_in[26];
  const float* mW2 = (const float*)d_in[27]; const float* mb2 = (const float*)d_in[28];
  float* out = (float*)d_out;

  float* ws    = (float*)d_ws;
  float* hA    = ws + WO_HA;
  float* hB    = ws + WO_HB;
  float* acc   = ws + WO_ACC;
  float* prevl = ws + WO_PREVL;
  float* prevt = ws + WO_PREVT;
  float* ltlog = ws + WO_LTLOG;

  // host-side key chain: key(42); 310x fold-like split (verified bit-exact)
  uint32_t kh = 0u, kl = 42u;
  AllK ak;
  for (int n = 0; n < 310; ++n) {
    uint32_t a0 = 0u, a1 = 0u; tf2x32(kh, kl, a0, a1);
    uint32_t b0 = 0u, b1 = 1u; tf2x32(kh, kl, b0, b1);
    ak.k[n][0] = b0; ak.k[n][1] = b1;
    kh = a0; kl = a1;
  }

  const bool useNoise = ws_size >= ((size_t)WO_NOISE + NOISE_FLOATS) * 4;
  float* noisep = useNoise ? (ws + WO_NOISE) : nullptr;

  prep_k<<<54, 256, 0, stream>>>(fW1, gW1, fW2, gW2, fW3, gW3, eW1, eW2,
                                 mW1, mW2, jW1, jW2, logits, ws);
  init_k<<<NROW / 4, 256, 0, stream>>>(type_, mask_, h0, eW1, eb1, eW2, eb2,
                                       hA, acc, ltlog, out);
  if (useNoise)
    noise_k<<<(310 * NBLK) / 4, 256, 0, stream>>>(noisep, ak);

  for (int s = 1; s <= 31; ++s) {
    const float* hs = (s & 1) ? hA : hB;
    float*       hd = (s & 1) ? hB : hA;
    SubK skc;
    for (int j = 0; j < ND_; ++j) {
      skc.k[j][0] = ak.k[(s - 1) * ND_ + j][0];
      skc.k[j][1] = ak.k[(s - 1) * ND_ + j][1];
    }
    const float* nin = useNoise ? (noisep + (size_t)(s - 1) * ND_ * NBLK * 64 * 8) : nullptr;
    euler_k<<<NBLK, 64, 0, stream>>>(time_, type_, mask_, ws,
                                     fb1, fb2, fb3, gb1, gb2, gb3, eb1, eb2, eW2,
                                     fW1, gW1, mb1, mb2, jb1, jb2,
                                     hs, hd, acc, prevl, prevt, ltlog, out,
                                     nin, s, skc);
  }
  reduce_k<<<1, 256, 0, stream>>>(acc, ltlog, out);
}